// Round 6
// baseline (152.835 us; speedup 1.0000x reference)
//
#include <hip/hip_runtime.h>
#include <hip/hip_bf16.h>
#include <math.h>

#define N_ROWS 8192
#define DIM 256
#define NCLS 128
// scale folded into normalized rows: sqrt((1/0.07) * log2(e))
#define ROW_SCALE 4.539816f
#define CLAMP_Y 14.426950408889634f   // 10 * log2(e)
#define NEG2C (-28.853900817779268f)  // -2 * CLAMP_Y
#define LN2F 0.6931471805599453f

typedef short bf16x8 __attribute__((ext_vector_type(8)));
typedef float f32x4 __attribute__((ext_vector_type(4)));

#define AS1 __attribute__((address_space(1)))
#define AS3 __attribute__((address_space(3)))

__device__ __forceinline__ void load16_to_lds(const void* g, void* lds) {
  // LDS dest = wave-uniform base (+ lane*16 added by HW); gptr is per-lane
  __builtin_amdgcn_global_load_lds((const AS1 void*)g, (AS3 void*)lds, 16, 0, 0);
}

__device__ __forceinline__ unsigned short f2bf(float x) {
  union { __hip_bfloat16 b; unsigned short u; } cv;
  cv.b = __float2bfloat16(x);
  return cv.u;
}

__device__ __forceinline__ float fast_exp2(float x) {
#if __has_builtin(__builtin_amdgcn_exp2f)
  return __builtin_amdgcn_exp2f(x);
#else
  return exp2f(x);
#endif
}

// clamp(x, -2C, 0) in one v_med3_f32
__device__ __forceinline__ float clamp_neg(float x) {
#if __has_builtin(__builtin_amdgcn_fmed3f)
  return __builtin_amdgcn_fmed3f(x, NEG2C, 0.0f);
#else
  return fminf(0.0f, fmaxf(NEG2C, x));
#endif
}

// ---------------- row-normalize*ROW_SCALE -> bf16, zero S/P -----------------
__global__ __launch_bounds__(256) void normalize_kernel(const float* __restrict__ f,
                                                        unsigned short* __restrict__ fnb,
                                                        float* __restrict__ S,
                                                        float* __restrict__ P) {
  const int row = blockIdx.x * 4 + (threadIdx.x >> 6);
  const int l = threadIdx.x & 63;
  const float4 v = ((const float4*)(f + (size_t)row * DIM))[l];
  float ss = v.x * v.x + v.y * v.y + v.z * v.z + v.w * v.w;
#pragma unroll
  for (int m = 32; m >= 1; m >>= 1) ss += __shfl_xor(ss, m, 64);
  const float inv = ROW_SCALE / fmaxf(sqrtf(ss), 1e-6f);
  ushort4 o;
  o.x = f2bf(v.x * inv);
  o.y = f2bf(v.y * inv);
  o.z = f2bf(v.z * inv);
  o.w = f2bf(v.w * inv);
  ((ushort4*)(fnb + (size_t)row * DIM))[l] = o;
  if (l == 0) { S[row] = 0.f; P[row] = 0.f; }
}

// ---------------- triangular-strip GEMM + exp/positive reductions -----------
// 544 blocks x 512 threads (8 waves, 2 wr x 4 wc): block = (bi, chunk of up
// to 2 j-strips of 256 cols). A (128x256 bf16, 64 KB) resident in LDS.
// B staged per phase as [256 j-rows][64 k] (32 KB) double-buffered: 4 phases
// per j-tile, 32 MFMA/wave/phase, ONE __syncthreads per phase. Next strip's
// phase-0 stages in the p=3 slot (parity preserved).
// NOTE __launch_bounds__(512, 1): on this toolchain the 2nd arg acts as min
// BLOCKS/CU (measured: (512,4)->VGPR 64, (512,2)->VGPR 128, both spilled).
// (512,1) -> 256-VGPR cap, no spill; 136 KB LDS forces 1 block/CU anyway.
// Accumulator biased by -CLAMP_Y: epilogue = v_med3 + exp2; diagonal
// contributes e=1 / pv=0, corrected in finalize.
__global__ __launch_bounds__(512, 1) void simloss_tri(
    const unsigned short* __restrict__ fnb, const int* __restrict__ labels,
    float* __restrict__ S, float* __restrict__ P) {
  __shared__ __align__(16) unsigned short Atile[128 * 256];   // 64 KB
  __shared__ __align__(16) unsigned short Bsh[2][256 * 64];   // 64 KB
  __shared__ float colbuf[256][2];                            // 2 KB
  __shared__ float rslice[3][128][2];                         // 3 KB

  const int tid = threadIdx.x;
  const int w = tid >> 6;   // wave 0..7
  const int l = tid & 63;
  const int wr = w >> 2;    // wave row group -> 64 rows
  const int wc = w & 3;     // wave col group -> 64 cols of the 256 strip
  const int ln15 = l & 15;
  const int q = l >> 4;

  // decode blockIdx.x -> (bi, chunk); bi has ceil(ns/2) chunks; sum=544
  int b = blockIdx.x, bi, ns = 0;
  for (bi = 0; bi < 64; ++bi) {
    ns = (65 - bi) >> 1;              // 256-wide strips for this bi
    const int nch = (ns + 1) >> 1;    // chunks of 2 strips
    if (b < nch) break;
    b -= nch;
  }
  const int ibase = bi * 128;
  const int t0 = b * 2;                            // first strip index
  const int jn = (ns - t0 < 2) ? (ns - t0) : 2;    // strips this block (1..2)
  const char* fnb_c = (const char*)fnb;

  // ---- stage A [128][256] bf16; 16B chunk slot s holds global chunk s^(r&7)
#pragma unroll
  for (int r = 0; r < 8; ++r) {
    const int off = r * 8192 + w * 1024 + l * 16;
    const int row = off >> 9;                      // 512 B per row
    const int c = ((off >> 4) & 31) ^ (row & 7);
    load16_to_lds(fnb_c + (size_t)(ibase + row) * 512 + c * 16,
                  (char*)Atile + r * 8192 + w * 1024);
  }

  // ---- cold stage B: strip t0, phase 0 -> Bsh[0]
  {
    const int jrow0 = ibase + t0 * 256;
    const int jrows = (N_ROWS - jrow0 < 256) ? (N_ROWS - jrow0) : 256;
#pragma unroll
    for (int r = 0; r < 4; ++r) {
      const int off = r * 8192 + w * 1024 + l * 16;
      const int row = off >> 7;                    // 128 B per B-row
      const int c = ((off >> 4) & 7) ^ (row & 7);
      const int sr = jrow0 + ((row < jrows) ? row : jrows - 1);
      load16_to_lds(fnb_c + (size_t)sr * 512 + c * 16,
                    (char*)&Bsh[0][0] + r * 8192 + w * 1024);
    }
  }

  int rowlab[16];
#pragma unroll
  for (int mi = 0; mi < 4; ++mi)
#pragma unroll
    for (int rg = 0; rg < 4; ++rg)
      rowlab[mi * 4 + rg] = labels[ibase + wr * 64 + mi * 16 + q * 4 + rg];

  float rs[16], rp[16];
#pragma unroll
  for (int t = 0; t < 16; ++t) { rs[t] = 0.f; rp[t] = 0.f; }

  __syncthreads();  // A + cold B0 staged

  for (int jt = 0; jt < jn; ++jt) {
    const int t = t0 + jt;
    const int jrow0 = ibase + t * 256;
    const int jrows = (N_ROWS - jrow0 < 256) ? (N_ROWS - jrow0) : 256;
    const bool cvalid = (wc * 64) < jrows;   // wave-uniform

    int labJ[4];
#pragma unroll
    for (int ni = 0; ni < 4; ++ni) {
      int idx = jrow0 + wc * 64 + ni * 16 + ln15;
      labJ[ni] = labels[(idx < N_ROWS) ? idx : (N_ROWS - 1)];
    }

    f32x4 acc[4][4];
#pragma unroll
    for (int mi = 0; mi < 4; ++mi)
#pragma unroll
      for (int ni = 0; ni < 4; ++ni) acc[mi][ni] = (f32x4)(-CLAMP_Y);

    // ---- 4 phases of K=64: stage(p+1) first, compute(p), one sync ----
#pragma unroll
    for (int p = 0; p < 4; ++p) {
      if (p < 3) {
        // stage phase p+1 of this strip -> other buffer (last read p-1)
#pragma unroll
        for (int r = 0; r < 4; ++r) {
          const int off = r * 8192 + w * 1024 + l * 16;
          const int row = off >> 7;
          const int c = ((off >> 4) & 7) ^ (row & 7);
          const int sr = jrow0 + ((row < jrows) ? row : jrows - 1);
          load16_to_lds(fnb_c + (size_t)sr * 512 + (p + 1) * 128 + c * 16,
                        (char*)&Bsh[(p + 1) & 1][0] + r * 8192 + w * 1024);
        }
      } else if (jt + 1 < jn) {
        // p==3 slot: next strip's phase 0 -> Bsh[0] (last read at p=2)
        const int jrow0n = jrow0 + 256;
        const int jrowsn = (N_ROWS - jrow0n < 256) ? (N_ROWS - jrow0n) : 256;
#pragma unroll
        for (int r = 0; r < 4; ++r) {
          const int off = r * 8192 + w * 1024 + l * 16;
          const int row = off >> 7;
          const int c = ((off >> 4) & 7) ^ (row & 7);
          const int sr = jrow0n + ((row < jrowsn) ? row : jrowsn - 1);
          load16_to_lds(fnb_c + (size_t)sr * 512 + c * 16,
                        (char*)&Bsh[0][0] + r * 8192 + w * 1024);
        }
      }
      // compute phase p from Bsh[p&1] (kk-split keeps frag liveness at 32)
      const char* bb = (const char*)&Bsh[p & 1][0];
#pragma unroll
      for (int kk = 0; kk < 2; ++kk) {
        bf16x8 af[4], bf[4];
#pragma unroll
        for (int mi = 0; mi < 4; ++mi) {
          const int row = wr * 64 + mi * 16 + ln15;
          const int c = (p * 8 + kk * 4 + q) ^ (row & 7);
          af[mi] = *(const bf16x8*)((const char*)Atile + row * 512 + c * 16);
        }
#pragma unroll
        for (int ni = 0; ni < 4; ++ni) {
          const int n = wc * 64 + ni * 16 + ln15;
          const int s = (kk * 4 + q) ^ (n & 7);
          bf[ni] = *(const bf16x8*)(bb + n * 128 + s * 16);
        }
#pragma unroll
        for (int mi = 0; mi < 4; ++mi)
#pragma unroll
          for (int ni = 0; ni < 4; ++ni)
            acc[mi][ni] = __builtin_amdgcn_mfma_f32_16x16x32_bf16(
                af[mi], bf[ni], acc[mi][ni], 0, 0, 0);
      }
      __syncthreads();  // drains this phase's stage issue; orders buffer reuse
    }

    // ---- epilogue: exp-sum + positive-sim accumulate (rows + cols) ----
    float cs[4], cp[4];
#pragma unroll
    for (int z = 0; z < 4; ++z) { cs[z] = 0.f; cp[z] = 0.f; }
    if (cvalid) {
#pragma unroll
      for (int mi = 0; mi < 4; ++mi)
#pragma unroll
        for (int ni = 0; ni < 4; ++ni)
#pragma unroll
          for (int rg = 0; rg < 4; ++rg) {
            const float yc = clamp_neg(acc[mi][ni][rg]);  // clamp*log2e - C
            const float e = fast_exp2(yc);
            const float pv = (labJ[ni] == rowlab[mi * 4 + rg]) ? yc : 0.0f;
            rs[mi * 4 + rg] += e;
            rp[mi * 4 + rg] += pv;
            cs[ni] += e;
            cp[ni] += pv;
          }
      // col sums: reduce over q (row sub-groups) within the wave
#pragma unroll
      for (int m = 16; m <= 32; m <<= 1)
#pragma unroll
        for (int ni = 0; ni < 4; ++ni) {
          cs[ni] += __shfl_xor(cs[ni], m, 64);
          cp[ni] += __shfl_xor(cp[ni], m, 64);
        }
      if (wr == 1 && q == 0) {
#pragma unroll
        for (int ni = 0; ni < 4; ++ni) {
          const int cl = wc * 64 + ni * 16 + ln15;
          colbuf[cl][0] = cs[ni];
          colbuf[cl][1] = cp[ni];
        }
      }
    }
    __syncthreads();
    // col sums -> rows of the j-strip via symmetry; skip the diagonal half
    // (t==0 && wc<2) and invalid halves
    if (cvalid && wr == 0 && q == 0 && !(t == 0 && wc < 2)) {
#pragma unroll
      for (int ni = 0; ni < 4; ++ni) {
        const int cl = wc * 64 + ni * 16 + ln15;
        atomicAdd(&S[jrow0 + cl], cs[ni] + colbuf[cl][0]);
        atomicAdd(&P[jrow0 + cl], cp[ni] + colbuf[cl][1]);
      }
    }
    // next write to colbuf is 4 phase-syncs away -> no extra barrier needed
  }

  // ---- row-sum flush: 16-lane reduce, 4-way wc combine in LDS, atomics ----
#pragma unroll
  for (int m = 1; m <= 8; m <<= 1)
#pragma unroll
    for (int z = 0; z < 16; ++z) {
      rs[z] += __shfl_xor(rs[z], m, 64);
      rp[z] += __shfl_xor(rp[z], m, 64);
    }
  if (wc > 0 && ln15 == 0) {
#pragma unroll
    for (int z = 0; z < 16; ++z) {
      const int rl = wr * 64 + (z >> 2) * 16 + q * 4 + (z & 3);
      rslice[wc - 1][rl][0] = rs[z];
      rslice[wc - 1][rl][1] = rp[z];
    }
  }
  __syncthreads();
  if (wc == 0 && ln15 == 0) {
#pragma unroll
    for (int z = 0; z < 16; ++z) {
      const int rl = wr * 64 + (z >> 2) * 16 + q * 4 + (z & 3);
      atomicAdd(&S[ibase + rl],
                rs[z] + rslice[0][rl][0] + rslice[1][rl][0] + rslice[2][rl][0]);
      atomicAdd(&P[ibase + rl],
                rp[z] + rslice[0][rl][1] + rslice[1][rl][1] + rslice[2][rl][1]);
    }
  }
}

// ---------------- finalize: label hist (LDS) + per-row loss + mean ----------
// With biased accumulator: S = sum_j exp(sim_c - 10) incl diag(=1);
// P = sum_{pos} (sim_c*log2e - C) with diag contributing 0  =>
// loss_i = log(S-1) - ln2 * P / cnt      (the +10/-10 cancel exactly)
__global__ __launch_bounds__(1024) void finalize_kernel(
    const float* __restrict__ S, const float* __restrict__ P,
    const int* __restrict__ labels, float* __restrict__ out) {
  __shared__ int h[NCLS];
  if (threadIdx.x < NCLS) h[threadIdx.x] = 0;
  __syncthreads();
  for (int i = threadIdx.x; i < N_ROWS; i += 1024) atomicAdd(&h[labels[i]], 1);
  __syncthreads();

  float lsum = 0.f, vsum = 0.f;
  for (int i = threadIdx.x; i < N_ROWS; i += 1024) {
    const int cnt = h[labels[i]] - 1;  // positives excluding self
    if (cnt > 0) {
      lsum += logf(S[i] - 1.0f) - LN2F * P[i] / (float)cnt;
      vsum += 1.0f;
    }
  }
#pragma unroll
  for (int m = 32; m >= 1; m >>= 1) {
    lsum += __shfl_xor(lsum, m, 64);
    vsum += __shfl_xor(vsum, m, 64);
  }
  __shared__ float ls[16], vs[16];
  const int wv = threadIdx.x >> 6;
  if ((threadIdx.x & 63) == 0) { ls[wv] = lsum; vs[wv] = vsum; }
  __syncthreads();
  if (threadIdx.x == 0) {
    float L = 0.f, V = 0.f;
    for (int k = 0; k < 16; ++k) { L += ls[k]; V += vs[k]; }
    out[0] = (V > 0.f) ? (L / fmaxf(V, 1.0f)) : 0.f;
  }
}

extern "C" void kernel_launch(void* const* d_in, const int* in_sizes, int n_in,
                              void* d_out, int out_size, void* d_ws, size_t ws_size,
                              hipStream_t stream) {
  const float* feat = (const float*)d_in[0];
  const int* labels = (const int*)d_in[1];
  float* out = (float*)d_out;

  char* ws = (char*)d_ws;
  unsigned short* fnb = (unsigned short*)ws;            // bf16 [8192][256], 4 MB
  float* S = (float*)(ws + (size_t)N_ROWS * DIM * 2);   // [8192]
  float* P = S + N_ROWS;                                // [8192]

  normalize_kernel<<<N_ROWS / 4, 256, 0, stream>>>(feat, fnb, S, P);
  simloss_tri<<<544, 512, 0, stream>>>(fnb, labels, S, P);
  finalize_kernel<<<1, 1024, 0, stream>>>(S, P, labels, out);
}

// Round 7
// 122.763 us; speedup vs baseline: 1.2450x; 1.2450x over previous
//
#include <hip/hip_runtime.h>
#include <hip/hip_bf16.h>
#include <math.h>

#define N_ROWS 8192
#define DIM 256
#define NCLS 128
// scale folded into normalized rows: sqrt((1/0.07) * log2(e))
#define ROW_SCALE 4.539816f
#define CLAMP_Y 14.426950408889634f   // 10 * log2(e)
#define NEG2C (-28.853900817779268f)  // -2 * CLAMP_Y
#define LN2F 0.6931471805599453f

typedef short bf16x8 __attribute__((ext_vector_type(8)));
typedef float f32x4 __attribute__((ext_vector_type(4)));

#define AS1 __attribute__((address_space(1)))
#define AS3 __attribute__((address_space(3)))

__device__ __forceinline__ void load16_to_lds(const void* g, void* lds) {
  // LDS dest = wave-uniform base (+ lane*16 added by HW); gptr is per-lane
  __builtin_amdgcn_global_load_lds((const AS1 void*)g, (AS3 void*)lds, 16, 0, 0);
}

__device__ __forceinline__ unsigned short f2bf(float x) {
  union { __hip_bfloat16 b; unsigned short u; } cv;
  cv.b = __float2bfloat16(x);
  return cv.u;
}

__device__ __forceinline__ float fast_exp2(float x) {
#if __has_builtin(__builtin_amdgcn_exp2f)
  return __builtin_amdgcn_exp2f(x);
#else
  return exp2f(x);
#endif
}

// clamp(x, -2C, 0) in one v_med3_f32
__device__ __forceinline__ float clamp_neg(float x) {
#if __has_builtin(__builtin_amdgcn_fmed3f)
  return __builtin_amdgcn_fmed3f(x, NEG2C, 0.0f);
#else
  return fminf(0.0f, fmaxf(NEG2C, x));
#endif
}

// ---------------- row-normalize*ROW_SCALE -> bf16, zero S/P -----------------
__global__ __launch_bounds__(256) void normalize_kernel(const float* __restrict__ f,
                                                        unsigned short* __restrict__ fnb,
                                                        float* __restrict__ S,
                                                        float* __restrict__ P) {
  const int row = blockIdx.x * 4 + (threadIdx.x >> 6);
  const int l = threadIdx.x & 63;
  const float4 v = ((const float4*)(f + (size_t)row * DIM))[l];
  float ss = v.x * v.x + v.y * v.y + v.z * v.z + v.w * v.w;
#pragma unroll
  for (int m = 32; m >= 1; m >>= 1) ss += __shfl_xor(ss, m, 64);
  const float inv = ROW_SCALE / fmaxf(sqrtf(ss), 1e-6f);
  ushort4 o;
  o.x = f2bf(v.x * inv);
  o.y = f2bf(v.y * inv);
  o.z = f2bf(v.z * inv);
  o.w = f2bf(v.w * inv);
  ((ushort4*)(fnb + (size_t)row * DIM))[l] = o;
  if (l == 0) { S[row] = 0.f; P[row] = 0.f; }
}

// ---------------- triangular streaming GEMM + exp/positive reductions -------
// 2080 blocks x 256 threads (4 waves, 2x2): block = one upper-tri tile
// (bi,bj), 128x128. m97-streaming structure: BOTH A (rows bi) and B (rows bj)
// staged per K-step as 128x32 bf16 tiles (8 KB each), double-buffered ->
// LDS = 33 KB -> 3-4 blocks/CU (vs 2 with the old A-resident 80 KB layout).
// That raises waves/SIMD from 2 to 3-4: this kernel is latency-bound
// (MfmaUtil+VALUBusy ~35%, no BW saturated), so TLP is the lever.
// launch_bounds(256,3): VGPR cap ~170 (R3 needed 116; spill tripwire =
// WRITE_SIZE). Per phase: stage next A+B (4 x gload_lds / thread), 8 ds_read
// + 16 MFMA per wave, one __syncthreads. 64-B LDS rows, chunk swizzle
// pos^((row>>1)&3) (proven in R3's B path). Accumulator biased by -CLAMP_Y:
// epilogue = v_med3 + exp2; diagonal contributes e=1 / pv=0, fixed in
// finalize. Col sums flow to rows of bj via symmetry (skip diagonal tile).
__global__ __launch_bounds__(256, 3) void simloss_tri(
    const unsigned short* __restrict__ fnb, const int* __restrict__ labels,
    float* __restrict__ S, float* __restrict__ P) {
  __shared__ __align__(16) unsigned short Ash[2][128 * 32];  // 16 KB
  __shared__ __align__(16) unsigned short Bsh[2][128 * 32];  // 16 KB
  __shared__ float redbuf[128][2];                           // 1 KB

  const int tid = threadIdx.x;
  const int w = tid >> 6;   // wave 0..3
  const int l = tid & 63;
  const int wr = w >> 1;    // wave row -> 64 rows
  const int wc = w & 1;     // wave col -> 64 cols
  const int ln15 = l & 15;
  const int q = l >> 4;

  // decode blockIdx.x -> (bi, bj): row bi has 64-bi tiles (bj = bi..63)
  int b = blockIdx.x, bi;
  for (bi = 0; bi < 64; ++bi) {
    const int nt = 64 - bi;
    if (b < nt) break;
    b -= nt;
  }
  const int bj = bi + b;
  const int ibase = bi * 128;
  const int jbase = bj * 128;
  const char* fnb_c = (const char*)fnb;

  // per-thread staging geometry (128 rows x 64 B): thread covers 2 x 16 B
  // r-loop offsets; row = off/64, slot = (off>>4)&3, src chunk = slot^swz(row)
  // ---- cold stage kt=0: A -> Ash[0], B -> Bsh[0]
#pragma unroll
  for (int r = 0; r < 2; ++r) {
    const int off = r * 4096 + tid * 16;
    const int row = off >> 6;
    const int c = ((off >> 4) & 3) ^ ((row >> 1) & 3);
    load16_to_lds(fnb_c + (size_t)(ibase + row) * 512 + c * 16,
                  (char*)&Ash[0][0] + r * 4096 + w * 1024);
    load16_to_lds(fnb_c + (size_t)(jbase + row) * 512 + c * 16,
                  (char*)&Bsh[0][0] + r * 4096 + w * 1024);
  }

  int rowlab[16];
#pragma unroll
  for (int mi = 0; mi < 4; ++mi)
#pragma unroll
    for (int rg = 0; rg < 4; ++rg)
      rowlab[mi * 4 + rg] = labels[ibase + wr * 64 + mi * 16 + q * 4 + rg];
  int labJ[4];
#pragma unroll
  for (int ni = 0; ni < 4; ++ni)
    labJ[ni] = labels[jbase + wc * 64 + ni * 16 + ln15];

  float rs[16], rp[16];
#pragma unroll
  for (int t = 0; t < 16; ++t) { rs[t] = 0.f; rp[t] = 0.f; }

  f32x4 acc[4][4];
#pragma unroll
  for (int mi = 0; mi < 4; ++mi)
#pragma unroll
    for (int ni = 0; ni < 4; ++ni) acc[mi][ni] = (f32x4)(-CLAMP_Y);

  __syncthreads();  // cold A0/B0 staged (syncthreads drains vmcnt)

  // ---- streaming K loop: stage kt+1 (A+B), compute kt, one sync per kt ----
#pragma unroll
  for (int kt = 0; kt < 8; ++kt) {
    if (kt < 7) {
#pragma unroll
      for (int r = 0; r < 2; ++r) {
        const int off = r * 4096 + tid * 16;
        const int row = off >> 6;
        const int c = ((off >> 4) & 3) ^ ((row >> 1) & 3);
        load16_to_lds(fnb_c + (size_t)(ibase + row) * 512 + (kt + 1) * 64 + c * 16,
                      (char*)&Ash[(kt + 1) & 1][0] + r * 4096 + w * 1024);
        load16_to_lds(fnb_c + (size_t)(jbase + row) * 512 + (kt + 1) * 64 + c * 16,
                      (char*)&Bsh[(kt + 1) & 1][0] + r * 4096 + w * 1024);
      }
    }
    const char* ab = (const char*)&Ash[kt & 1][0];
    const char* bb = (const char*)&Bsh[kt & 1][0];
    bf16x8 af[4], bfr[4];
#pragma unroll
    for (int mi = 0; mi < 4; ++mi) {
      const int row = wr * 64 + mi * 16 + ln15;
      const int c = q ^ ((row >> 1) & 3);
      af[mi] = *(const bf16x8*)(ab + row * 64 + c * 16);
    }
#pragma unroll
    for (int ni = 0; ni < 4; ++ni) {
      const int n = wc * 64 + ni * 16 + ln15;
      const int c = q ^ ((n >> 1) & 3);
      bfr[ni] = *(const bf16x8*)(bb + n * 64 + c * 16);
    }
#pragma unroll
    for (int mi = 0; mi < 4; ++mi)
#pragma unroll
      for (int ni = 0; ni < 4; ++ni)
        acc[mi][ni] = __builtin_amdgcn_mfma_f32_16x16x32_bf16(af[mi], bfr[ni],
                                                              acc[mi][ni], 0, 0, 0);
    if (kt < 7) __syncthreads();  // drains stage(kt+1); orders buffer reuse
  }

  // ---- epilogue: exp-sum + positive-sim accumulate (rows + cols) ----
  float cs[4], cp[4];
#pragma unroll
  for (int t = 0; t < 4; ++t) { cs[t] = 0.f; cp[t] = 0.f; }
#pragma unroll
  for (int mi = 0; mi < 4; ++mi)
#pragma unroll
    for (int ni = 0; ni < 4; ++ni)
#pragma unroll
      for (int rg = 0; rg < 4; ++rg) {
        const float yc = clamp_neg(acc[mi][ni][rg]);  // clamp(sim)*log2e - C
        const float e = fast_exp2(yc);
        const float pv = (labJ[ni] == rowlab[mi * 4 + rg]) ? yc : 0.0f;
        rs[mi * 4 + rg] += e;
        rp[mi * 4 + rg] += pv;
        cs[ni] += e;
        cp[ni] += pv;
      }

  // col sums -> rows of bj via symmetry (skip diagonal tile)
#pragma unroll
  for (int m = 16; m <= 32; m <<= 1)
#pragma unroll
    for (int t = 0; t < 4; ++t) {
      cs[t] += __shfl_xor(cs[t], m, 64);
      cp[t] += __shfl_xor(cp[t], m, 64);
    }
  __syncthreads();  // all waves past kt=7 reads (Bsh dead); redbuf fresh
  if (wr == 1 && q == 0) {
#pragma unroll
    for (int ni = 0; ni < 4; ++ni) {
      const int cl = wc * 64 + ni * 16 + ln15;
      redbuf[cl][0] = cs[ni];
      redbuf[cl][1] = cp[ni];
    }
  }
  __syncthreads();
  if (wr == 0 && q == 0 && bj != bi) {
#pragma unroll
    for (int ni = 0; ni < 4; ++ni) {
      const int cl = wc * 64 + ni * 16 + ln15;
      atomicAdd(&S[jbase + cl], cs[ni] + redbuf[cl][0]);
      atomicAdd(&P[jbase + cl], cp[ni] + redbuf[cl][1]);
    }
  }

  // ---- row-sum flush: 16-lane reduce, wc-pair combine in LDS, atomics ----
#pragma unroll
  for (int m = 1; m <= 8; m <<= 1)
#pragma unroll
    for (int t = 0; t < 16; ++t) {
      rs[t] += __shfl_xor(rs[t], m, 64);
      rp[t] += __shfl_xor(rp[t], m, 64);
    }
  __syncthreads();  // col-phase redbuf reads done before overwrite
  if (wc == 1 && ln15 == 0) {
#pragma unroll
    for (int t = 0; t < 16; ++t) {
      const int rl = wr * 64 + (t >> 2) * 16 + q * 4 + (t & 3);
      redbuf[rl][0] = rs[t];
      redbuf[rl][1] = rp[t];
    }
  }
  __syncthreads();
  if (wc == 0 && ln15 == 0) {
#pragma unroll
    for (int t = 0; t < 16; ++t) {
      const int rl = wr * 64 + (t >> 2) * 16 + q * 4 + (t & 3);
      atomicAdd(&S[ibase + rl], rs[t] + redbuf[rl][0]);
      atomicAdd(&P[ibase + rl], rp[t] + redbuf[rl][1]);
    }
  }
}

// ---------------- finalize: label hist (LDS) + per-row loss + mean ----------
// With biased accumulator: S = sum_j exp(sim_c - 10) incl diag(=1);
// P = sum_{pos} (sim_c*log2e - C) with diag contributing 0  =>
// loss_i = log(S-1) - ln2 * P / cnt      (the +10/-10 cancel exactly)
__global__ __launch_bounds__(1024) void finalize_kernel(
    const float* __restrict__ S, const float* __restrict__ P,
    const int* __restrict__ labels, float* __restrict__ out) {
  __shared__ int h[NCLS];
  if (threadIdx.x < NCLS) h[threadIdx.x] = 0;
  __syncthreads();
  for (int i = threadIdx.x; i < N_ROWS; i += 1024) atomicAdd(&h[labels[i]], 1);
  __syncthreads();

  float lsum = 0.f, vsum = 0.f;
  for (int i = threadIdx.x; i < N_ROWS; i += 1024) {
    const int cnt = h[labels[i]] - 1;  // positives excluding self
    if (cnt > 0) {
      lsum += logf(S[i] - 1.0f) - LN2F * P[i] / (float)cnt;
      vsum += 1.0f;
    }
  }
#pragma unroll
  for (int m = 32; m >= 1; m >>= 1) {
    lsum += __shfl_xor(lsum, m, 64);
    vsum += __shfl_xor(vsum, m, 64);
  }
  __shared__ float ls[16], vs[16];
  const int wv = threadIdx.x >> 6;
  if ((threadIdx.x & 63) == 0) { ls[wv] = lsum; vs[wv] = vsum; }
  __syncthreads();
  if (threadIdx.x == 0) {
    float L = 0.f, V = 0.f;
    for (int k = 0; k < 16; ++k) { L += ls[k]; V += vs[k]; }
    out[0] = (V > 0.f) ? (L / fmaxf(V, 1.0f)) : 0.f;
  }
}

extern "C" void kernel_launch(void* const* d_in, const int* in_sizes, int n_in,
                              void* d_out, int out_size, void* d_ws, size_t ws_size,
                              hipStream_t stream) {
  const float* feat = (const float*)d_in[0];
  const int* labels = (const int*)d_in[1];
  float* out = (float*)d_out;

  char* ws = (char*)d_ws;
  unsigned short* fnb = (unsigned short*)ws;            // bf16 [8192][256], 4 MB
  float* S = (float*)(ws + (size_t)N_ROWS * DIM * 2);   // [8192]
  float* P = S + N_ROWS;                                // [8192]

  normalize_kernel<<<N_ROWS / 4, 256, 0, stream>>>(feat, fnb, S, P);
  simloss_tri<<<2080, 256, 0, stream>>>(fnb, labels, S, P);
  finalize_kernel<<<1, 1024, 0, stream>>>(S, P, labels, out);
}